// Round 1
// baseline (1215.881 us; speedup 1.0000x reference)
//
#include <hip/hip_runtime.h>
#include <hip/hip_bf16.h>

#define N_NODES 50000
#define N_EDGES 600000
#define HIDDEN 128
#define GROWS 16  // nodes per block in qkv kernel

// ---------------------------------------------------------------------------
// Kernel 1: QKV projection.  out[n,o] = sum_i x[n,i] * W[o,i]   (x @ W^T)
// grid.y selects which of Wq/Wk/Wv -> q/k/v.
// W staged in LDS with +1 padding (row stride 129) so lanes reading
// wl[o][i] with o = lane hit distinct banks ((o+i)%32).
// ---------------------------------------------------------------------------
__global__ __launch_bounds__(256) void qkv_kernel(
    const float* __restrict__ x,
    const float* __restrict__ Wq, const float* __restrict__ Wk,
    const float* __restrict__ Wv,
    float* __restrict__ q, float* __restrict__ k, float* __restrict__ v,
    int n_nodes)
{
    __shared__ float wl[128][129];
    __shared__ float xl[GROWS][129];

    const float* W = (blockIdx.y == 0) ? Wq : (blockIdx.y == 1 ? Wk : Wv);
    float* outp    = (blockIdx.y == 0) ? q  : (blockIdx.y == 1 ? k  : v);

    const int tid   = threadIdx.x;
    const int node0 = blockIdx.x * GROWS;

    // Stage W: 128x128 floats, as 4096 float4 loads across 256 threads.
    for (int idx = tid; idx < 128 * 32; idx += 256) {
        int r  = idx >> 5;        // row
        int c4 = idx & 31;        // which float4 in row
        float4 val = *reinterpret_cast<const float4*>(W + r * 128 + c4 * 4);
        wl[r][c4 * 4 + 0] = val.x;
        wl[r][c4 * 4 + 1] = val.y;
        wl[r][c4 * 4 + 2] = val.z;
        wl[r][c4 * 4 + 3] = val.w;
    }
    // Stage x tile: GROWS x 128 floats.
    for (int idx = tid; idx < GROWS * 32; idx += 256) {
        int r  = idx >> 5;
        int c4 = idx & 31;
        int node = node0 + r;
        float4 val = make_float4(0.f, 0.f, 0.f, 0.f);
        if (node < n_nodes)
            val = *reinterpret_cast<const float4*>(x + (size_t)node * 128 + c4 * 4);
        xl[r][c4 * 4 + 0] = val.x;
        xl[r][c4 * 4 + 1] = val.y;
        xl[r][c4 * 4 + 2] = val.z;
        xl[r][c4 * 4 + 3] = val.w;
    }
    __syncthreads();

    const int o  = tid & 31;   // output col base (o, o+32, o+64, o+96)
    const int rg = tid >> 5;   // row group 0..7 -> rows rg*2, rg*2+1

    float acc[2][4] = {{0.f, 0.f, 0.f, 0.f}, {0.f, 0.f, 0.f, 0.f}};

#pragma unroll 4
    for (int i = 0; i < 128; ++i) {
        float x0 = xl[rg * 2 + 0][i];
        float x1 = xl[rg * 2 + 1][i];
        float w0 = wl[o +  0][i];
        float w1 = wl[o + 32][i];
        float w2 = wl[o + 64][i];
        float w3 = wl[o + 96][i];
        acc[0][0] += x0 * w0; acc[0][1] += x0 * w1;
        acc[0][2] += x0 * w2; acc[0][3] += x0 * w3;
        acc[1][0] += x1 * w0; acc[1][1] += x1 * w1;
        acc[1][2] += x1 * w2; acc[1][3] += x1 * w3;
    }

#pragma unroll
    for (int rr = 0; rr < 2; ++rr) {
        int node = node0 + rg * 2 + rr;
        if (node < n_nodes) {
            float* op = outp + (size_t)node * 128;
#pragma unroll
            for (int j = 0; j < 4; ++j)
                op[o + 32 * j] = acc[rr][j];
        }
    }
}

// ---------------------------------------------------------------------------
// Kernel 2: per-edge attention + scatter-add.
// 32 lanes per edge; lane l handles elements [4l, 4l+3] (head = l>>2).
// alpha_h = (sum_d q[dst][h,d] * w[e][h,d] * k[src][h,d]) / sqrt(16) * cutoff
// out[dst] += alpha_h * v[src]   (atomicAdd, f32, device scope)
// ---------------------------------------------------------------------------
__global__ __launch_bounds__(256) void edge_kernel(
    const float* __restrict__ q, const float* __restrict__ k,
    const float* __restrict__ v, const float* __restrict__ w_ij,
    const int* __restrict__ edge_index, const float* __restrict__ cutoff,
    float* __restrict__ out, int n_edges)
{
    const int lane = threadIdx.x & 31;
    const int eidx = blockIdx.x * (blockDim.x >> 5) + (threadIdx.x >> 5);
    if (eidx >= n_edges) return;

    const int src = edge_index[eidx];            // j
    const int dst = edge_index[n_edges + eidx];  // i
    const float c = cutoff[eidx];

    const float4 qv = *reinterpret_cast<const float4*>(q + (size_t)dst * 128 + lane * 4);
    const float4 kv = *reinterpret_cast<const float4*>(k + (size_t)src * 128 + lane * 4);
    const float4 vv = *reinterpret_cast<const float4*>(v + (size_t)src * 128 + lane * 4);
    const float4 wv = *reinterpret_cast<const float4*>(w_ij + (size_t)eidx * 128 + lane * 4);

    float s = qv.x * wv.x * kv.x + qv.y * wv.y * kv.y +
              qv.z * wv.z * kv.z + qv.w * wv.w * kv.w;

    // reduce over the 4 lanes of this head (lanes sharing lane>>2)
    s += __shfl_xor(s, 1);
    s += __shfl_xor(s, 2);

    const float alpha = s * 0.25f * c;  // 1/sqrt(HEAD_DIM=16) = 0.25

    float* op = out + (size_t)dst * 128 + lane * 4;
    atomicAdd(op + 0, alpha * vv.x);
    atomicAdd(op + 1, alpha * vv.y);
    atomicAdd(op + 2, alpha * vv.z);
    atomicAdd(op + 3, alpha * vv.w);
}

extern "C" void kernel_launch(void* const* d_in, const int* in_sizes, int n_in,
                              void* d_out, int out_size, void* d_ws, size_t ws_size,
                              hipStream_t stream) {
    const float* x    = (const float*)d_in[0];
    const float* w_ij = (const float*)d_in[1];
    const int* eidx   = (const int*)d_in[2];
    const float* cut  = (const float*)d_in[3];
    const float* Wq   = (const float*)d_in[4];
    const float* Wk   = (const float*)d_in[5];
    const float* Wv   = (const float*)d_in[6];
    float* out = (float*)d_out;

    const size_t nq = (size_t)N_NODES * HIDDEN;
    float* q = (float*)d_ws;
    float* k = q + nq;
    float* v = k + nq;

    // Zero the output: atomics accumulate and the harness does not re-poison
    // between timed replays.
    hipMemsetAsync(d_out, 0, (size_t)out_size * sizeof(float), stream);

    // QKV projection: grid.y = {q,k,v}
    dim3 ggrid((N_NODES + GROWS - 1) / GROWS, 3);
    qkv_kernel<<<ggrid, 256, 0, stream>>>(x, Wq, Wk, Wv, q, k, v, N_NODES);

    // Edge attention + scatter
    const int edges_per_block = 256 / 32;
    dim3 egrid((N_EDGES + edges_per_block - 1) / edges_per_block);
    edge_kernel<<<egrid, 256, 0, stream>>>(q, k, v, w_ij, eidx, cut, out, N_EDGES);
}

// Round 2
// 520.075 us; speedup vs baseline: 2.3379x; 2.3379x over previous
//
#include <hip/hip_runtime.h>
#include <hip/hip_bf16.h>

#define N_NODES 50000
#define N_EDGES 600000
#define HIDDEN 128
#define GROWS 32  // nodes per block in qkv kernel (4 rows/thread)

// ---------------------------------------------------------------------------
// Kernel 1: QKV projection.  out[n,o] = sum_i x[n,i] * W[o,i]   (x @ W^T)
// 4x4 register blocking: thread (o = tid&31, rg = tid>>5) computes rows
// rg*4..rg*4+3, cols {o, o+32, o+64, o+96}.  x read as float4 along i
// (broadcast within half-wave); W read as b32, stride 129 -> bank (o+i)%32,
// conflict-free.
// ---------------------------------------------------------------------------
__global__ __launch_bounds__(256) void qkv_kernel(
    const float* __restrict__ x,
    const float* __restrict__ Wq, const float* __restrict__ Wk,
    const float* __restrict__ Wv,
    float* __restrict__ q, float* __restrict__ k, float* __restrict__ v,
    int n_nodes)
{
    __shared__ float wl[128][129];
    __shared__ float xl[GROWS][132];  // 132: float4-aligned rows

    const float* W = (blockIdx.y == 0) ? Wq : (blockIdx.y == 1 ? Wk : Wv);
    float* outp    = (blockIdx.y == 0) ? q  : (blockIdx.y == 1 ? k  : v);

    const int tid   = threadIdx.x;
    const int node0 = blockIdx.x * GROWS;

    // Stage W: 128x128 floats, 4096 float4 loads across 256 threads.
    for (int idx = tid; idx < 128 * 32; idx += 256) {
        int r  = idx >> 5;
        int c4 = idx & 31;
        float4 val = *reinterpret_cast<const float4*>(W + r * 128 + c4 * 4);
        wl[r][c4 * 4 + 0] = val.x;
        wl[r][c4 * 4 + 1] = val.y;
        wl[r][c4 * 4 + 2] = val.z;
        wl[r][c4 * 4 + 3] = val.w;
    }
    // Stage x tile: GROWS x 128 floats.
    for (int idx = tid; idx < GROWS * 32; idx += 256) {
        int r  = idx >> 5;
        int c4 = idx & 31;
        int node = node0 + r;
        float4 val = make_float4(0.f, 0.f, 0.f, 0.f);
        if (node < n_nodes)
            val = *reinterpret_cast<const float4*>(x + (size_t)node * 128 + c4 * 4);
        *reinterpret_cast<float4*>(&xl[r][c4 * 4]) = val;
    }
    __syncthreads();

    const int o  = tid & 31;
    const int rg = tid >> 5;

    float acc[4][4];
#pragma unroll
    for (int a = 0; a < 4; ++a)
#pragma unroll
        for (int b = 0; b < 4; ++b) acc[a][b] = 0.f;

    for (int i = 0; i < 128; i += 4) {
        float xa[4][4];
#pragma unroll
        for (int rr = 0; rr < 4; ++rr) {
            float4 xv = *reinterpret_cast<const float4*>(&xl[rg * 4 + rr][i]);
            xa[rr][0] = xv.x; xa[rr][1] = xv.y; xa[rr][2] = xv.z; xa[rr][3] = xv.w;
        }
#pragma unroll
        for (int d = 0; d < 4; ++d) {
            float w0 = wl[o +  0][i + d];
            float w1 = wl[o + 32][i + d];
            float w2 = wl[o + 64][i + d];
            float w3 = wl[o + 96][i + d];
#pragma unroll
            for (int rr = 0; rr < 4; ++rr) {
                acc[rr][0] += xa[rr][d] * w0;
                acc[rr][1] += xa[rr][d] * w1;
                acc[rr][2] += xa[rr][d] * w2;
                acc[rr][3] += xa[rr][d] * w3;
            }
        }
    }

#pragma unroll
    for (int rr = 0; rr < 4; ++rr) {
        int node = node0 + rg * 4 + rr;
        if (node < n_nodes) {
            float* op = outp + (size_t)node * 128;
#pragma unroll
            for (int j = 0; j < 4; ++j)
                op[o + 32 * j] = acc[rr][j];
        }
    }
}

// ---------------------------------------------------------------------------
// CSR build: histogram -> scan -> slot scatter
// ---------------------------------------------------------------------------
__global__ __launch_bounds__(256) void hist_kernel(
    const int* __restrict__ edge_index, int* __restrict__ hist, int n_edges)
{
    int e = blockIdx.x * 256 + threadIdx.x;
    if (e < n_edges) atomicAdd(&hist[edge_index[n_edges + e]], 1);
}

// Single block, 1024 threads: exclusive scan of hist[0..n-1] -> offsets,
// cursor; offsets[n] = total.
__global__ __launch_bounds__(1024) void scan_kernel(
    const int* __restrict__ hist, int* __restrict__ offsets,
    int* __restrict__ cursor, int n)
{
    __shared__ int part[1024];
    const int T = 1024;
    const int t = threadIdx.x;
    const int chunk = (n + T - 1) / T;
    const int start = t * chunk;

    int s = 0;
    for (int i = 0; i < chunk; ++i) {
        int idx = start + i;
        if (idx < n) s += hist[idx];
    }
    part[t] = s;
    __syncthreads();
    for (int off = 1; off < T; off <<= 1) {
        int val = 0;
        if (t >= off) val = part[t - off];
        __syncthreads();
        if (t >= off) part[t] += val;
        __syncthreads();
    }
    int run = (t == 0) ? 0 : part[t - 1];
    for (int i = 0; i < chunk; ++i) {
        int idx = start + i;
        if (idx < n) {
            offsets[idx] = run;
            cursor[idx]  = run;
            run += hist[idx];
        }
    }
    if (t == T - 1) offsets[n] = part[T - 1];
}

__global__ __launch_bounds__(256) void scatter_kernel(
    const int* __restrict__ edge_index, const float* __restrict__ cutoff,
    int* __restrict__ cursor, int* __restrict__ csr_src,
    int* __restrict__ csr_eid, float* __restrict__ csr_cut, int n_edges)
{
    int e = blockIdx.x * 256 + threadIdx.x;
    if (e >= n_edges) return;
    int src = edge_index[e];
    int dst = edge_index[n_edges + e];
    int slot = atomicAdd(&cursor[dst], 1);
    csr_src[slot] = src;
    csr_eid[slot] = e;
    csr_cut[slot] = cutoff[e];
}

// ---------------------------------------------------------------------------
// Gather: 32 lanes per node, loop incoming edges, write out once (no atomics).
// lane l handles elements [4l,4l+3]; head = l>>2.
// ---------------------------------------------------------------------------
__global__ __launch_bounds__(256) void gather_kernel(
    const float* __restrict__ q, const float* __restrict__ k,
    const float* __restrict__ v, const float* __restrict__ w_ij,
    const int* __restrict__ offsets, const int* __restrict__ csr_src,
    const int* __restrict__ csr_eid, const float* __restrict__ csr_cut,
    float* __restrict__ out, int n_nodes)
{
    const int lane = threadIdx.x & 31;
    const int node = blockIdx.x * 8 + (threadIdx.x >> 5);
    if (node >= n_nodes) return;

    const float4 qv = *reinterpret_cast<const float4*>(q + (size_t)node * 128 + lane * 4);
    float4 acc = make_float4(0.f, 0.f, 0.f, 0.f);

    const int beg = offsets[node];
    const int end = offsets[node + 1];

    for (int s = beg; s < end; ++s) {
        const int src  = csr_src[s];
        const int e    = csr_eid[s];
        const float c  = csr_cut[s];
        const float4 wv = *reinterpret_cast<const float4*>(w_ij + (size_t)e * 128 + lane * 4);
        const float4 kv = *reinterpret_cast<const float4*>(k + (size_t)src * 128 + lane * 4);
        const float4 vv = *reinterpret_cast<const float4*>(v + (size_t)src * 128 + lane * 4);

        float sdot = qv.x * wv.x * kv.x + qv.y * wv.y * kv.y +
                     qv.z * wv.z * kv.z + qv.w * wv.w * kv.w;
        sdot += __shfl_xor(sdot, 1);
        sdot += __shfl_xor(sdot, 2);

        const float alpha = sdot * 0.25f * c;  // 1/sqrt(16)=0.25
        acc.x += alpha * vv.x;
        acc.y += alpha * vv.y;
        acc.z += alpha * vv.z;
        acc.w += alpha * vv.w;
    }

    *reinterpret_cast<float4*>(out + (size_t)node * 128 + lane * 4) = acc;
}

extern "C" void kernel_launch(void* const* d_in, const int* in_sizes, int n_in,
                              void* d_out, int out_size, void* d_ws, size_t ws_size,
                              hipStream_t stream) {
    const float* x    = (const float*)d_in[0];
    const float* w_ij = (const float*)d_in[1];
    const int* eidx   = (const int*)d_in[2];
    const float* cut  = (const float*)d_in[3];
    const float* Wq   = (const float*)d_in[4];
    const float* Wk   = (const float*)d_in[5];
    const float* Wv   = (const float*)d_in[6];
    float* out = (float*)d_out;

    const size_t nq = (size_t)N_NODES * HIDDEN;
    float* q = (float*)d_ws;
    float* k = q + nq;
    float* v = k + nq;
    int* hist    = (int*)(v + nq);
    int* offsets = hist + N_NODES;
    int* cursor  = offsets + N_NODES + 1;
    int* csr_src = cursor + N_NODES;
    int* csr_eid = csr_src + N_EDGES;
    float* csr_cut = (float*)(csr_eid + N_EDGES);

    // hist must be zero at the start of every call (atomics accumulate).
    hipMemsetAsync(hist, 0, N_NODES * sizeof(int), stream);

    // QKV projection: grid.y = {q,k,v}
    dim3 ggrid((N_NODES + GROWS - 1) / GROWS, 3);
    qkv_kernel<<<ggrid, 256, 0, stream>>>(x, Wq, Wk, Wv, q, k, v, N_NODES);

    // CSR build
    dim3 egrid((N_EDGES + 255) / 256);
    hist_kernel<<<egrid, 256, 0, stream>>>(eidx, hist, N_EDGES);
    scan_kernel<<<1, 1024, 0, stream>>>(hist, offsets, cursor, N_NODES);
    scatter_kernel<<<egrid, 256, 0, stream>>>(eidx, cut, cursor, csr_src,
                                              csr_eid, csr_cut, N_EDGES);

    // Gather (writes every output element exactly once; no d_out memset needed)
    dim3 ngrid((N_NODES + 7) / 8);
    gather_kernel<<<ngrid, 256, 0, stream>>>(q, k, v, w_ij, offsets, csr_src,
                                             csr_eid, csr_cut, out, N_NODES);
}

// Round 3
// 388.655 us; speedup vs baseline: 3.1284x; 1.3381x over previous
//
#include <hip/hip_runtime.h>
#include <hip/hip_bf16.h>

#define N_NODES 50000
#define N_EDGES 600000
#define HIDDEN 128

typedef __attribute__((ext_vector_type(8))) short bf16x8;
typedef __attribute__((ext_vector_type(4))) float f32x4;

// f32 -> bf16 round-to-nearest-even (bit trick; inputs are normal randoms)
__device__ __forceinline__ short f2bf(float f) {
    unsigned u = __builtin_bit_cast(unsigned, f);
    u += 0x7fff + ((u >> 16) & 1);
    return (short)(u >> 16);
}

// ---------------------------------------------------------------------------
// QKV projection via bf16 MFMA.  out[n,o] = sum_i x[n,i] * W[o,i]  (x @ W^T)
// Block: 512 threads (8 waves), M-tile = 64 nodes, all 3*128 output cols.
// x tile: f32->bf16 into LDS, 16B chunks swizzled (ch ^ (row&7)) -> 2-way max.
// W: each wave owns 3 column-tiles (16 cols each) of the 24 total
// (3 matrices x 8); B-fragments converted f32->bf16 into 48 VGPRs, L2-served.
// MFMA 16x16x32: A lane l: row=l&15, k=(l>>4)*8+j ; B lane l: col=l&15,
// same k ; C/D: col=lane&15, row=(lane>>4)*4+reg (m89-verified).
// ---------------------------------------------------------------------------
__global__ __launch_bounds__(512, 4) void qkv_mfma_kernel(
    const float* __restrict__ x,
    const float* __restrict__ Wq, const float* __restrict__ Wk,
    const float* __restrict__ Wv,
    float* __restrict__ q, float* __restrict__ k, float* __restrict__ v,
    int n_nodes)
{
    __shared__ bf16x8 xs[1024];  // 64 rows x 16 chunks (16 B each), swizzled

    const int tid   = threadIdx.x;
    const int node0 = blockIdx.x * 64;

    // Stage x tile: 1024 chunks, 2 per thread. Coalesced 32B f32 reads.
    for (int i = 0; i < 2; ++i) {
        int idx = tid + i * 512;
        int row = idx >> 4;
        int ch  = idx & 15;
        int node = node0 + row;
        bf16x8 c = {0, 0, 0, 0, 0, 0, 0, 0};
        if (node < n_nodes) {
            const float* xp = x + (size_t)node * 128 + ch * 8;
            float4 f0 = *reinterpret_cast<const float4*>(xp);
            float4 f1 = *reinterpret_cast<const float4*>(xp + 4);
            c[0] = f2bf(f0.x); c[1] = f2bf(f0.y); c[2] = f2bf(f0.z); c[3] = f2bf(f0.w);
            c[4] = f2bf(f1.x); c[5] = f2bf(f1.y); c[6] = f2bf(f1.z); c[7] = f2bf(f1.w);
        }
        xs[row * 16 + (ch ^ (row & 7))] = c;
    }

    const int wave = tid >> 6;
    const int lane = tid & 63;
    const int ln16 = lane & 15;
    const int kg   = lane >> 4;   // k-subgroup 0..3

    // Load this wave's 3 coltiles of W into registers (bf16 B-fragments).
    bf16x8 wfrag[3][4];
    const int ctbase = wave * 3;
#pragma unroll
    for (int t = 0; t < 3; ++t) {
        int ct = ctbase + t;
        const float* Wm = (ct < 8) ? Wq : (ct < 16 ? Wk : Wv);
        int colbase = (ct & 7) * 16;
        const float* wrow = Wm + (size_t)(colbase + ln16) * 128;
#pragma unroll
        for (int s = 0; s < 4; ++s) {
            const float* wp = wrow + s * 32 + kg * 8;
            float4 f0 = *reinterpret_cast<const float4*>(wp);
            float4 f1 = *reinterpret_cast<const float4*>(wp + 4);
            bf16x8 c;
            c[0] = f2bf(f0.x); c[1] = f2bf(f0.y); c[2] = f2bf(f0.z); c[3] = f2bf(f0.w);
            c[4] = f2bf(f1.x); c[5] = f2bf(f1.y); c[6] = f2bf(f1.z); c[7] = f2bf(f1.w);
            wfrag[t][s] = c;
        }
    }

    __syncthreads();

    // 4 row-groups of 16 rows each; A-fragments reused across 3 coltiles.
    for (int rg = 0; rg < 4; ++rg) {
        bf16x8 afrag[4];
        int row = rg * 16 + ln16;
#pragma unroll
        for (int s = 0; s < 4; ++s) {
            int ch = s * 4 + kg;
            afrag[s] = xs[row * 16 + (ch ^ (row & 7))];
        }
#pragma unroll
        for (int t = 0; t < 3; ++t) {
            f32x4 acc = {0.f, 0.f, 0.f, 0.f};
#pragma unroll
            for (int s = 0; s < 4; ++s)
                acc = __builtin_amdgcn_mfma_f32_16x16x32_bf16(afrag[s], wfrag[t][s], acc, 0, 0, 0);
            int ct = ctbase + t;
            float* outp = (ct < 8) ? q : (ct < 16 ? k : v);
            int colbase = (ct & 7) * 16;
            int rbase = node0 + rg * 16 + kg * 4;
#pragma unroll
            for (int i2 = 0; i2 < 4; ++i2) {
                int node = rbase + i2;
                if (node < n_nodes)
                    outp[(size_t)node * 128 + colbase + ln16] = acc[i2];
            }
        }
    }
}

// ---------------------------------------------------------------------------
// CSR build: histogram -> scan -> slot scatter
// ---------------------------------------------------------------------------
__global__ __launch_bounds__(256) void hist_kernel(
    const int* __restrict__ edge_index, int* __restrict__ hist, int n_edges)
{
    int e = blockIdx.x * 256 + threadIdx.x;
    if (e < n_edges) atomicAdd(&hist[edge_index[n_edges + e]], 1);
}

__global__ __launch_bounds__(1024) void scan_kernel(
    const int* __restrict__ hist, int* __restrict__ offsets,
    int* __restrict__ cursor, int n)
{
    __shared__ int part[1024];
    const int T = 1024;
    const int t = threadIdx.x;
    const int chunk = (n + T - 1) / T;
    const int start = t * chunk;

    int s = 0;
    for (int i = 0; i < chunk; ++i) {
        int idx = start + i;
        if (idx < n) s += hist[idx];
    }
    part[t] = s;
    __syncthreads();
    for (int off = 1; off < T; off <<= 1) {
        int val = 0;
        if (t >= off) val = part[t - off];
        __syncthreads();
        if (t >= off) part[t] += val;
        __syncthreads();
    }
    int run = (t == 0) ? 0 : part[t - 1];
    for (int i = 0; i < chunk; ++i) {
        int idx = start + i;
        if (idx < n) {
            offsets[idx] = run;
            cursor[idx]  = run;
            run += hist[idx];
        }
    }
    if (t == T - 1) offsets[n] = part[T - 1];
}

__global__ __launch_bounds__(256) void scatter_kernel(
    const int* __restrict__ edge_index, const float* __restrict__ cutoff,
    int* __restrict__ cursor, int* __restrict__ csr_src,
    int* __restrict__ csr_eid, float* __restrict__ csr_cut, int n_edges)
{
    int e = blockIdx.x * 256 + threadIdx.x;
    if (e >= n_edges) return;
    int src = edge_index[e];
    int dst = edge_index[n_edges + e];
    int slot = atomicAdd(&cursor[dst], 1);
    csr_src[slot] = src;
    csr_eid[slot] = e;
    csr_cut[slot] = cutoff[e];
}

// ---------------------------------------------------------------------------
// Gather: 32 lanes per node, loop incoming edges, write out once (no atomics).
// ---------------------------------------------------------------------------
__global__ __launch_bounds__(256) void gather_kernel(
    const float* __restrict__ q, const float* __restrict__ k,
    const float* __restrict__ v, const float* __restrict__ w_ij,
    const int* __restrict__ offsets, const int* __restrict__ csr_src,
    const int* __restrict__ csr_eid, const float* __restrict__ csr_cut,
    float* __restrict__ out, int n_nodes)
{
    const int lane = threadIdx.x & 31;
    const int node = blockIdx.x * 8 + (threadIdx.x >> 5);
    if (node >= n_nodes) return;

    const float4 qv = *reinterpret_cast<const float4*>(q + (size_t)node * 128 + lane * 4);
    float4 acc = make_float4(0.f, 0.f, 0.f, 0.f);

    const int beg = offsets[node];
    const int end = offsets[node + 1];

    for (int s = beg; s < end; ++s) {
        const int src  = csr_src[s];
        const int e    = csr_eid[s];
        const float c  = csr_cut[s];
        const float4 wv = *reinterpret_cast<const float4*>(w_ij + (size_t)e * 128 + lane * 4);
        const float4 kv = *reinterpret_cast<const float4*>(k + (size_t)src * 128 + lane * 4);
        const float4 vv = *reinterpret_cast<const float4*>(v + (size_t)src * 128 + lane * 4);

        float sdot = qv.x * wv.x * kv.x + qv.y * wv.y * kv.y +
                     qv.z * wv.z * kv.z + qv.w * wv.w * kv.w;
        sdot += __shfl_xor(sdot, 1);
        sdot += __shfl_xor(sdot, 2);

        const float alpha = sdot * 0.25f * c;  // 1/sqrt(16)=0.25
        acc.x += alpha * vv.x;
        acc.y += alpha * vv.y;
        acc.z += alpha * vv.z;
        acc.w += alpha * vv.w;
    }

    *reinterpret_cast<float4*>(out + (size_t)node * 128 + lane * 4) = acc;
}

extern "C" void kernel_launch(void* const* d_in, const int* in_sizes, int n_in,
                              void* d_out, int out_size, void* d_ws, size_t ws_size,
                              hipStream_t stream) {
    const float* x    = (const float*)d_in[0];
    const float* w_ij = (const float*)d_in[1];
    const int* eidx   = (const int*)d_in[2];
    const float* cut  = (const float*)d_in[3];
    const float* Wq   = (const float*)d_in[4];
    const float* Wk   = (const float*)d_in[5];
    const float* Wv   = (const float*)d_in[6];
    float* out = (float*)d_out;

    const size_t nq = (size_t)N_NODES * HIDDEN;
    float* q = (float*)d_ws;
    float* k = q + nq;
    float* v = k + nq;
    int* hist    = (int*)(v + nq);
    int* offsets = hist + N_NODES;
    int* cursor  = offsets + N_NODES + 1;
    int* csr_src = cursor + N_NODES;
    int* csr_eid = csr_src + N_EDGES;
    float* csr_cut = (float*)(csr_eid + N_EDGES);

    // hist must be zero at the start of every call (atomics accumulate).
    hipMemsetAsync(hist, 0, N_NODES * sizeof(int), stream);

    // QKV projection (MFMA): one kernel computes q, k, v.
    dim3 ggrid((N_NODES + 63) / 64);
    qkv_mfma_kernel<<<ggrid, 512, 0, stream>>>(x, Wq, Wk, Wv, q, k, v, N_NODES);

    // CSR build
    dim3 egrid((N_EDGES + 255) / 256);
    hist_kernel<<<egrid, 256, 0, stream>>>(eidx, hist, N_EDGES);
    scan_kernel<<<1, 1024, 0, stream>>>(hist, offsets, cursor, N_NODES);
    scatter_kernel<<<egrid, 256, 0, stream>>>(eidx, cut, cursor, csr_src,
                                              csr_eid, csr_cut, N_EDGES);

    // Gather (writes every output element exactly once)
    dim3 ngrid((N_NODES + 7) / 8);
    gather_kernel<<<ngrid, 256, 0, stream>>>(q, k, v, w_ij, offsets, csr_src,
                                             csr_eid, csr_cut, out, N_NODES);
}